// Round 1
// baseline (326.970 us; speedup 1.0000x reference)
//
#include <hip/hip_runtime.h>
#include <stdint.h>

typedef unsigned long long u64;

#define CIN    256
#define COUT   256
#define HW     56
#define NPIX   (HW * HW)        // 3136
#define PADW   58
#define PPIX   (PADW * PADW)    // 3364
#define NBATCH 32

// ---------------------------------------------------------------------------
// Pack sign(x) bits along Cin into u64 words, into a zero-padded 58x58 grid.
// Thread -> (n, pixel, word-quarter). Lanes: wq fastest then p => loads of
// x[n][wq*64+j][p] are 4 groups of 16 consecutive pixels per wave (4 full
// 64B lines per load instr). Stores of u64 words are fully coalesced.
// ---------------------------------------------------------------------------
__global__ __launch_bounds__(256) void pack_x_kernel(const float* __restrict__ x,
                                                     u64* __restrict__ xb) {
    int g   = blockIdx.x * 256 + threadIdx.x;   // total = 32*3136*4, exact
    int wq  = g & 3;
    int rem = g >> 2;
    int p   = rem % NPIX;
    int n   = rem / NPIX;
    const float* xp = x + ((size_t)(n * CIN + wq * 64)) * NPIX + p;
    u64 word = 0;
#pragma unroll
    for (int j = 0; j < 64; ++j) {
        word |= (u64)(xp[(size_t)j * NPIX] > 0.0f) << j;
    }
    int h = p / HW, w = p % HW;
    xb[((size_t)n * PPIX + (size_t)(h + 1) * PADW + (w + 1)) * 4 + wq] = word;
}

// ---------------------------------------------------------------------------
// Pack sign(W) bits along Cin: wb[co][k][q] , k = kh*3+kw, q = ci/64.
// ---------------------------------------------------------------------------
__global__ __launch_bounds__(256) void pack_w_kernel(const float* __restrict__ wt,
                                                     u64* __restrict__ wb) {
    int g = blockIdx.x * 256 + threadIdx.x;     // 9 blocks * 256 = 2304
    if (g >= COUT * 9) return;
    int co = g / 9, k = g % 9;
#pragma unroll
    for (int q = 0; q < 4; ++q) {
        u64 word = 0;
#pragma unroll
        for (int j = 0; j < 64; ++j) {
            float v = wt[((size_t)(co * CIN + q * 64 + j)) * 9 + k];
            word |= (u64)(v > 0.0f) << j;
        }
        wb[((size_t)co * 9 + k) * 4 + q] = word;
    }
}

// ---------------------------------------------------------------------------
// Precompute the affine epilogue per (co, border-class):
//   out = A[co][cls] - B[co] * popc_total
// where popc_total counts mismatches over all 9 taps with zeroed padded words,
// and A folds both the valid-bit count and the garbage correction for the
// invalid (padded) taps: A = alpha*(256*vcnt + 2*wclsum), B = 2*alpha.
// Border class: ch = {0: h==0, 1: interior, 2: h==55}, same for cw; cls=ch*3+cw.
// ---------------------------------------------------------------------------
__global__ __launch_bounds__(256) void make_ab_kernel(const u64* __restrict__ wb,
                                                      const float* __restrict__ alpha,
                                                      float* __restrict__ A,
                                                      float* __restrict__ B) {
    int co = blockIdx.x * 256 + threadIdx.x;
    if (co >= COUT) return;
    int kpop[9];
#pragma unroll
    for (int k = 0; k < 9; ++k) {
        int s = 0;
#pragma unroll
        for (int q = 0; q < 4; ++q) s += __popcll(wb[((size_t)co * 9 + k) * 4 + q]);
        kpop[k] = s;
    }
    float al = alpha[co];
    B[co] = 2.0f * al;
#pragma unroll
    for (int cls = 0; cls < 9; ++cls) {
        int ch = cls / 3, cw = cls % 3;
        int wcl = 0, vcnt = 0;
#pragma unroll
        for (int k = 0; k < 9; ++k) {
            int kh = k / 3, kw = k % 3;
            bool inv = (kh == 0 && ch == 0) || (kh == 2 && ch == 2) ||
                       (kw == 0 && cw == 0) || (kw == 2 && cw == 2);
            if (inv) wcl += kpop[k]; else vcnt++;
        }
        A[co * 9 + cls] = al * (float)(256 * vcnt + 2 * wcl);
    }
}

// ---------------------------------------------------------------------------
// XNOR conv. Thread = one output pixel, loops over 64 couts (grid.z chunks).
// Neighborhood (9 taps x 4 u64 = 72 VGPR) loaded once per thread; W words
// are wave-uniform (co is a uniform loop var, read-only buffer) -> scalar
// loads. Stores: lanes are consecutive pixels -> 256B coalesced per co.
// ---------------------------------------------------------------------------
__global__ __launch_bounds__(256) void conv_kernel(const u64* __restrict__ xb,
                                                   const u64* __restrict__ wb,
                                                   const float* __restrict__ A,
                                                   const float* __restrict__ B,
                                                   float* __restrict__ out) {
    int tid   = threadIdx.x;
    int ptile = blockIdx.x;     // 13 tiles of 256 pixels
    int n     = blockIdx.y;     // 32
    int chunk = blockIdx.z;     // 4 chunks of 64 couts
    int p = ptile * 256 + tid;
    if (p >= NPIX) return;
    int h = p / HW, w = p % HW;

    // padded grid: output (h,w) needs padded rows h..h+2, cols w..w+2
    u64 xn[9][4];
    const u64* xbase = xb + ((size_t)n * PPIX + (size_t)h * PADW + w) * 4;
#pragma unroll
    for (int dh = 0; dh < 3; ++dh)
#pragma unroll
        for (int dw = 0; dw < 3; ++dw)
#pragma unroll
            for (int q = 0; q < 4; ++q)
                xn[dh * 3 + dw][q] = xbase[((size_t)dh * PADW + dw) * 4 + q];

    int ch  = (h == 0) ? 0 : ((h == HW - 1) ? 2 : 1);
    int cw  = (w == 0) ? 0 : ((w == HW - 1) ? 2 : 1);
    int cls = ch * 3 + cw;

    int co0 = chunk * 64;
    const u64*   wp = wb + (size_t)co0 * 36;
    float*       op = out + ((size_t)(n * COUT + co0)) * NPIX + p;
    const float* Ap = A + co0 * 9 + cls;
    const float* Bp = B + co0;

    for (int c = 0; c < 64; ++c) {
        int acc0 = 0, acc1 = 0;
#pragma unroll
        for (int k = 0; k < 9; ++k) {
#pragma unroll
            for (int q = 0; q < 4; ++q) {
                int pc = __popcll(xn[k][q] ^ wp[k * 4 + q]);
                if ((k ^ q) & 1) acc1 += pc; else acc0 += pc;
            }
        }
        op[0] = Ap[c * 9] - Bp[c] * (float)(acc0 + acc1);
        op += NPIX;
        wp += 36;
    }
}

// ---------------------------------------------------------------------------
extern "C" void kernel_launch(void* const* d_in, const int* in_sizes, int n_in,
                              void* d_out, int out_size, void* d_ws, size_t ws_size,
                              hipStream_t stream) {
    const float* x     = (const float*)d_in[0];
    const float* wt    = (const float*)d_in[1];
    const float* alpha = (const float*)d_in[2];
    float* out = (float*)d_out;

    char* ws = (char*)d_ws;
    u64* xb = (u64*)ws;                                       // 3,444,736 B
    size_t xb_bytes = (size_t)NBATCH * PPIX * 4 * sizeof(u64);
    u64* wb = (u64*)(ws + xb_bytes);                          // 73,728 B
    size_t wb_bytes = (size_t)COUT * 9 * 4 * sizeof(u64);
    float* A = (float*)(ws + xb_bytes + wb_bytes);            // 9,216 B
    float* B = A + COUT * 9;                                  // 1,024 B

    // zero the padded bit-grid (border ring must be 0 each call; ws is poisoned)
    hipMemsetAsync(xb, 0, xb_bytes, stream);

    pack_x_kernel<<<dim3(NBATCH * NPIX * 4 / 256), 256, 0, stream>>>(x, xb);
    pack_w_kernel<<<dim3(9), 256, 0, stream>>>(wt, wb);
    make_ab_kernel<<<dim3(1), 256, 0, stream>>>(wb, alpha, A, B);
    conv_kernel<<<dim3(13, NBATCH, 4), 256, 0, stream>>>(xb, wb, A, B, out);
}

// Round 2
// 309.552 us; speedup vs baseline: 1.0563x; 1.0563x over previous
//
#include <hip/hip_runtime.h>
#include <stdint.h>

typedef unsigned long long u64;

#define CIN    256
#define COUT   256
#define HW     56
#define NPIX   (HW * HW)        // 3136
#define PADW   58
#define PPIX   (PADW * PADW)    // 3364
#define NBATCH 32

// ---------------------------------------------------------------------------
// Pack sign(x) bits along Cin into u64 words in a zero-padded 58x58 grid.
// Block = 256 consecutive pixels of one (n, q); a wave reads 64 consecutive
// pixels of one channel per load instr => 256B contiguous (full lines).
// ---------------------------------------------------------------------------
__global__ __launch_bounds__(256) void pack_x_kernel(const float* __restrict__ x,
                                                     u64* __restrict__ xb) {
    int p = blockIdx.x * 256 + threadIdx.x;
    int n = blockIdx.y;
    int q = blockIdx.z;
    if (p >= NPIX) return;
    const float* xp = x + ((size_t)(n * CIN + q * 64)) * NPIX + p;
    u64 word = 0;
#pragma unroll
    for (int j = 0; j < 64; ++j) {
        word |= (u64)(xp[(size_t)j * NPIX] > 0.0f) << j;
    }
    int h = p / HW, w = p % HW;
    xb[((size_t)n * PPIX + (size_t)(h + 1) * PADW + (w + 1)) * 4 + q] = word;
}

// ---------------------------------------------------------------------------
// Fused pack-W + epilogue-constant kernel. One block (1 wave) per cout.
// Lane j holds w[co][q*64+j][k]; __ballot(v>0) across the 64 lanes IS the
// packed u64 word. kpop computed uniformly on all lanes (mask is uniform).
//   out = A[co][cls] - B[co]*popc_total ;  A = alpha*(256*vcnt + 2*wcl),
//   B = 2*alpha. cls = border class (h==0 / interior / h==55) x (same for w).
// ---------------------------------------------------------------------------
__global__ __launch_bounds__(64) void packw_ab_kernel(const float* __restrict__ wt,
                                                      const float* __restrict__ alpha,
                                                      u64* __restrict__ wb,
                                                      float* __restrict__ A,
                                                      float* __restrict__ B) {
    int co   = blockIdx.x;
    int lane = threadIdx.x;
    u64 myword = 0;
    int kpop[9];
#pragma unroll
    for (int k = 0; k < 9; ++k) {
        int kp = 0;
#pragma unroll
        for (int q = 0; q < 4; ++q) {
            float v = wt[((size_t)(co * CIN + q * 64 + lane)) * 9 + k];
            u64 mask = __ballot(v > 0.0f);
            kp += __popcll(mask);
            if (lane == k * 4 + q) myword = mask;
        }
        kpop[k] = kp;
    }
    if (lane < 36) wb[(size_t)co * 36 + lane] = myword;
    float al = alpha[co];
    if (lane == 0) B[co] = 2.0f * al;
    if (lane < 9) {
        int ch = lane / 3, cw = lane % 3;
        int wcl = 0, vcnt = 0;
#pragma unroll
        for (int k = 0; k < 9; ++k) {
            int kh = k / 3, kw = k % 3;
            bool inv = (kh == 0 && ch == 0) || (kh == 2 && ch == 2) ||
                       (kw == 0 && cw == 0) || (kw == 2 && cw == 2);
            if (inv) wcl += kpop[k]; else vcnt++;
        }
        A[co * 9 + lane] = al * (float)(256 * vcnt + 2 * wcl);
    }
}

// ---------------------------------------------------------------------------
// XNOR conv. Thread = one output pixel, loops over 64 couts (grid.z chunks).
// __launch_bounds__(256,4): VGPR cap 128 so the 9x4 u64 neighborhood (72
// VGPR) stays RESIDENT across the co-loop (r1: compiler chose 48 VGPR and
// re-loaded x words every iteration => 2x VALU). W words are wave-uniform
// => scalar s_load path. 4 popcount chains (one per q) for ILP; v_bcnt
// accumulate fuses the adds.
// ---------------------------------------------------------------------------
__global__ __launch_bounds__(256, 4) void conv_kernel(const u64* __restrict__ xb,
                                                      const u64* __restrict__ wb,
                                                      const float* __restrict__ A,
                                                      const float* __restrict__ B,
                                                      float* __restrict__ out) {
    int tid   = threadIdx.x;
    int ptile = blockIdx.x;     // 13 tiles of 256 pixels
    int n     = blockIdx.y;     // 32
    int chunk = blockIdx.z;     // 4 chunks of 64 couts
    int p = ptile * 256 + tid;
    if (p >= NPIX) return;
    int h = p / HW, w = p % HW;

    // padded grid: output (h,w) needs padded rows h..h+2, cols w..w+2
    u64 xn[9][4];
    const u64* xbase = xb + ((size_t)n * PPIX + (size_t)h * PADW + w) * 4;
#pragma unroll
    for (int dh = 0; dh < 3; ++dh)
#pragma unroll
        for (int dw = 0; dw < 3; ++dw)
#pragma unroll
            for (int q = 0; q < 4; ++q)
                xn[dh * 3 + dw][q] = xbase[((size_t)dh * PADW + dw) * 4 + q];

    int ch  = (h == 0) ? 0 : ((h == HW - 1) ? 2 : 1);
    int cw  = (w == 0) ? 0 : ((w == HW - 1) ? 2 : 1);
    int cls = ch * 3 + cw;

    int co0 = chunk * 64;
    const u64*   wp = wb + (size_t)co0 * 36;
    float*       op = out + ((size_t)(n * COUT + co0)) * NPIX + p;
    const float* Ap = A + co0 * 9 + cls;
    const float* Bp = B + co0;

    for (int c = 0; c < 64; ++c) {
        int acc[4] = {0, 0, 0, 0};
#pragma unroll
        for (int k = 0; k < 9; ++k) {
#pragma unroll
            for (int q = 0; q < 4; ++q) {
                acc[q] += __popcll(xn[k][q] ^ wp[k * 4 + q]);
            }
        }
        int pc = (acc[0] + acc[1]) + (acc[2] + acc[3]);
        op[0] = Ap[c * 9] - Bp[c] * (float)pc;
        op += NPIX;
        wp += 36;
    }
}

// ---------------------------------------------------------------------------
extern "C" void kernel_launch(void* const* d_in, const int* in_sizes, int n_in,
                              void* d_out, int out_size, void* d_ws, size_t ws_size,
                              hipStream_t stream) {
    const float* x     = (const float*)d_in[0];
    const float* wt    = (const float*)d_in[1];
    const float* alpha = (const float*)d_in[2];
    float* out = (float*)d_out;

    char* ws = (char*)d_ws;
    u64* xb = (u64*)ws;                                       // 3,444,736 B
    size_t xb_bytes = (size_t)NBATCH * PPIX * 4 * sizeof(u64);
    u64* wb = (u64*)(ws + xb_bytes);                          // 73,728 B
    size_t wb_bytes = (size_t)COUT * 9 * 4 * sizeof(u64);
    float* A = (float*)(ws + xb_bytes + wb_bytes);            // 9,216 B
    float* B = A + COUT * 9;                                  // 1,024 B

    // zero the padded bit-grid (border ring must be 0 each call; ws is poisoned)
    hipMemsetAsync(xb, 0, xb_bytes, stream);

    pack_x_kernel<<<dim3(13, NBATCH, 4), 256, 0, stream>>>(x, xb);
    packw_ab_kernel<<<dim3(COUT), 64, 0, stream>>>(wt, alpha, wb, A, B);
    conv_kernel<<<dim3(13, NBATCH, 4), 256, 0, stream>>>(xb, wb, A, B, out);
}